// Round 1
// baseline (132.704 us; speedup 1.0000x reference)
//
#include <hip/hip_runtime.h>
#include <float.h>
#include <math.h>

#define KP 500000
#define KN 25000
#define KK 30
#define KD 128

// ---------------------------------------------------------------------------
// Kernel 1: e[p] = softplus( dot(z_feature[p], W[0:128]) + dot(z_others[p], W[128:256]) )
// 32 lanes per pair; lane l loads float4 at column l*4 of each tensor.
// ---------------------------------------------------------------------------
__global__ __launch_bounds__(256) void edge_score_kernel(
    const float* __restrict__ zf, const float* __restrict__ zo,
    const float* __restrict__ W, float* __restrict__ e, int P)
{
    const int lane = threadIdx.x & 31;                   // lane within 32-group
    const float4 w1 = *(const float4*)(W + lane * 4);        // W[0:128]
    const float4 w2 = *(const float4*)(W + 128 + lane * 4);  // W[128:256]

    long pair = (long)blockIdx.x * 8 + (threadIdx.x >> 5);   // 8 pairs / 256-thread block
    const long pstride = (long)gridDim.x * 8;

    for (; pair < P; pair += pstride) {
        const float4 a = *(const float4*)(zf + pair * KD + lane * 4);
        const float4 b = *(const float4*)(zo + pair * KD + lane * 4);
        float s = a.x * w1.x + a.y * w1.y + a.z * w1.z + a.w * w1.w
                + b.x * w2.x + b.y * w2.y + b.z * w2.z + b.w * w2.w;
        #pragma unroll
        for (int off = 16; off; off >>= 1)
            s += __shfl_xor(s, off, 32);
        if (lane == 0) {
            // numerically stable softplus = max(x,0) + log1p(exp(-|x|))
            e[pair] = fmaxf(s, 0.0f) + log1pf(expf(-fabsf(s)));
        }
    }
}

// ---------------------------------------------------------------------------
// Kernel 2: per output row r in [0, N+1): r==0 -> zeros; else node n = r-1:
//   masked softmax over the <=30 neighbor scores, then
//   out[r][d] = sum_k alpha[k] * z_others[idx_k - 1][d]
// One 64-lane wave per row; each lane owns a float2 column slice.
// ---------------------------------------------------------------------------
__global__ __launch_bounds__(256) void node_gather_kernel(
    const float* __restrict__ e, const float* __restrict__ zo,
    const int* __restrict__ scope, float* __restrict__ out, int Nrows)
{
    const int wave = threadIdx.x >> 6;
    const int lane = threadIdx.x & 63;
    const int r = blockIdx.x * 4 + wave;
    if (r >= Nrows) return;

    const int col = lane * 2;
    if (r == 0) {
        *(float2*)(out + col) = make_float2(0.f, 0.f);
        return;
    }
    const long n = r - 1;

    // lanes 0..29 hold this node's neighbor index and gathered edge score
    int   idx = 0;
    float ev  = 0.f;
    if (lane < KK) {
        idx = scope[n * KK + lane];
        if (idx > 0) ev = e[idx - 1];
    }

    // masked softmax over the wave (invalid lanes contribute -FLT_MAX / 0)
    const bool valid = (ev != 0.f);
    float logit = valid ? ev : -FLT_MAX;
    float m = logit;
    #pragma unroll
    for (int off = 32; off; off >>= 1)
        m = fmaxf(m, __shfl_xor(m, off, 64));

    float ex = valid ? expf(ev - m) : 0.f;
    float denom = ex;
    #pragma unroll
    for (int off = 32; off; off >>= 1)
        denom += __shfl_xor(denom, off, 64);
    denom = (denom > 0.f) ? denom : 1.f;
    const float alpha = ex / denom;

    // weighted gather-accumulate: each lane owns columns [col, col+1]
    float2 acc = make_float2(0.f, 0.f);
    #pragma unroll
    for (int k = 0; k < KK; ++k) {
        const int ik = __shfl(idx, k, 64);        // wave-uniform
        if (ik > 0) {
            const float ak = __shfl(alpha, k, 64);
            const float2 z = *(const float2*)(zo + (long)(ik - 1) * KD + col);
            acc.x += ak * z.x;
            acc.y += ak * z.y;
        }
    }
    *(float2*)(out + (long)r * KD + col) = acc;
}

extern "C" void kernel_launch(void* const* d_in, const int* in_sizes, int n_in,
                              void* d_out, int out_size, void* d_ws, size_t ws_size,
                              hipStream_t stream) {
    const float* zf    = (const float*)d_in[0];   // [P, D]
    const float* zo    = (const float*)d_in[1];   // [P, D]
    const int*   scope = (const int*)d_in[2];     // [N, K]
    const float* W     = (const float*)d_in[3];   // [2D, 1]
    float* out = (float*)d_out;                   // [(N+1), D]
    float* e   = (float*)d_ws;                    // [P] scratch

    const int P = in_sizes[0] / KD;
    const int N = in_sizes[2] / KK;

    // Kernel 1: edge scores
    {
        const int pairs_per_block = 8;
        const int grid = (P + pairs_per_block - 1) / pairs_per_block;
        edge_score_kernel<<<grid, 256, 0, stream>>>(zf, zo, W, e, P);
    }
    // Kernel 2: softmax + weighted gather (rows 0..N, row 0 = zeros)
    {
        const int nrows = N + 1;
        const int grid = (nrows + 3) / 4;
        node_gather_kernel<<<grid, 256, 0, stream>>>(e, zo, scope, out, nrows);
    }
}